// Round 7
// baseline (128.031 us; speedup 1.0000x reference)
//
#include <hip/hip_runtime.h>
#include <hip/hip_bf16.h>

// B=16, T=2048, C=384, H=64. out = softmax((x Wq)(x Wk)^T / sqrt(C)) (x Wv)
// ws (bf16): Qb[32768*64] | Kb[32768*64] | Vt[16][64][2048] | Wt[6*192*64]
// R10: flash reverted to R8 (reg staging beats global_load_lds here: reg
// prefetch loads stay in flight ACROSS the barrier, DMA forces vmcnt(0)
// before s_barrier -> serialized; setprio removed: 4-wave lockstep blocks
// are GEMM-like, m190 null/negative). qkv_proj reworked: wave owns 48
// OUTPUT COLUMNS (3 n-tiles) x all 64 rows instead of 16 rows x 192 cols.
// Old: b-frag reads had no wv -> all 4 waves read the same 24 W frags per
// chunk (4x redundant). New per-wave-chunk reads: 8 a + 6 b = 14 vs 26.

typedef __bf16 bf16;
typedef __attribute__((ext_vector_type(8))) __bf16 bf16x8;
typedef __attribute__((ext_vector_type(4))) __bf16 bf16x4;
typedef __attribute__((ext_vector_type(4))) float f32x4;

#define SCALE_LOG2E (0.051031036307982884f * 1.4426950408889634f)

// swizzled element pointer into a [64][64] bf16 tile (128 B rows):
// byte = row*128 + (cbyte ^ ((row&7)<<4)); bijective, keeps 16B/8B alignment.
__device__ __forceinline__ bf16* tp(bf16* base, int row, int cbyte) {
    return (bf16*)((char*)base + row * 128 + (cbyte ^ ((row & 7) << 4)));
}

// ---------------------------------------------------------------------------
// Kernel 0: pack W^T, Wt[ck][h][c'] (c = ck*64+c', h in [0,192) = Wq|Wk|Wv).
// ---------------------------------------------------------------------------
__global__ void pack_w(const float* __restrict__ Wq, const float* __restrict__ Wk,
                       const float* __restrict__ Wv, bf16* __restrict__ Wt) {
    int idx = blockIdx.x * 256 + threadIdx.x;      // 0..73727
    int cc = idx & 63;
    int hh = (idx >> 6) % 192;
    int ck = idx / 12288;
    const float* W = (hh < 64) ? Wq : (hh < 128 ? Wk : Wv);
    Wt[idx] = (bf16)W[(ck * 64 + cc) * 64 + (hh & 63)];
}

// ---------------------------------------------------------------------------
// Kernel 1: QKV projection. 64 rows x 192 cols per block, 256 thr (4 waves).
// Wave wv computes cols [wv*48, wv*48+48) (n-tiles j=0..2, global n=wv*3+j)
// for ALL 64 rows (rt=0..3). Per chunk per wave: 6 b-frag + 8 a-frag reads
// (was 24 b + 2 a with row-split -- b-frags were wave-redundant).
// mfma D: col=l16 (W col within tile), row=quad*4+reg (x row within tile).
// ---------------------------------------------------------------------------
__global__ __launch_bounds__(256) void qkv_proj(const float* __restrict__ x,
                                                const bf16* __restrict__ Wt,
                                                bf16* __restrict__ Qb,
                                                bf16* __restrict__ Kb,
                                                bf16* __restrict__ Vtg) {
    __shared__ __align__(16) bf16 Xs[2][64 * 72];
    __shared__ __align__(16) bf16 Ws[2][192 * 72];

    const int tid = threadIdx.x;
    const int wv = tid >> 6, lane = tid & 63, quad = lane >> 4, l16 = lane & 15;
    const int row0 = blockIdx.x * 64;

    f32x4 acc[12];                                 // [rt][j] -> acc[rt*3+j]
#pragma unroll
    for (int n = 0; n < 12; n++) acc[n] = (f32x4){0.f, 0.f, 0.f, 0.f};

    float4 xpre[4];
    bf16x8 wpre[6];
#pragma unroll
    for (int k = 0; k < 4; k++) {
        int g = tid + k * 256;
        xpre[k] = *(const float4*)(x + (long)(row0 + (g >> 4)) * 384 + (g & 15) * 4);
    }
#pragma unroll
    for (int k = 0; k < 6; k++)
        wpre[k] = *(const bf16x8*)(Wt + (tid + k * 256) * 8);

    for (int ck = 0; ck < 6; ck++) {
        bf16* Xc = Xs[ck & 1];
        bf16* Wc = Ws[ck & 1];
#pragma unroll
        for (int k = 0; k < 4; k++) {
            int g = tid + k * 256;
            float4 xv = xpre[k];
            *(bf16x4*)(&Xc[(g >> 4) * 72 + (g & 15) * 4]) =
                (bf16x4){(bf16)xv.x, (bf16)xv.y, (bf16)xv.z, (bf16)xv.w};
        }
#pragma unroll
        for (int k = 0; k < 6; k++) {
            int g = tid + k * 256;
            *(bf16x8*)(&Wc[(g >> 3) * 72 + (g & 7) * 8]) = wpre[k];
        }
        if (ck < 5) {
#pragma unroll
            for (int k = 0; k < 4; k++) {
                int g = tid + k * 256;
                xpre[k] = *(const float4*)(x + (long)(row0 + (g >> 4)) * 384 +
                                           (ck + 1) * 64 + (g & 15) * 4);
            }
#pragma unroll
            for (int k = 0; k < 6; k++)
                wpre[k] = *(const bf16x8*)(Wt + (ck + 1) * 12288 + (tid + k * 256) * 8);
        }
        __syncthreads();
#pragma unroll
        for (int kh = 0; kh < 2; kh++) {
            bf16x8 bb[3];
#pragma unroll
            for (int j = 0; j < 3; j++)
                bb[j] = *(bf16x8*)(&Wc[((wv * 3 + j) * 16 + l16) * 72 + kh * 32 + quad * 8]);
#pragma unroll
            for (int rt = 0; rt < 4; rt++) {
                bf16x8 a = *(bf16x8*)(&Xc[(rt * 16 + l16) * 72 + kh * 32 + quad * 8]);
#pragma unroll
                for (int j = 0; j < 3; j++)
                    acc[rt * 3 + j] = __builtin_amdgcn_mfma_f32_16x16x32_bf16(
                        a, bb[j], acc[rt * 3 + j], 0, 0, 0);
            }
        }
    }

    // epilogue: scatter acc into Q (scaled, row-major), K (row-major),
    // V (h-major) staging; n = wv*3+j decides the target (wave-uniform).
    __syncthreads();
#pragma unroll
    for (int rt = 0; rt < 4; rt++) {
#pragma unroll
        for (int j = 0; j < 3; j++) {
            const int n = wv * 3 + j;
            const int row = rt * 16 + quad * 4;
#pragma unroll
            for (int r = 0; r < 4; r++) {
                float v = acc[rt * 3 + j][r];
                if (n < 4)
                    Xs[0][(row + r) * 72 + n * 16 + l16] = (bf16)(v * SCALE_LOG2E);
                else if (n < 8)
                    Xs[1][(row + r) * 72 + (n - 4) * 16 + l16] = (bf16)v;
                else
                    Ws[0][((n - 8) * 16 + l16) * 72 + row + r] = (bf16)v;
            }
        }
    }
    __syncthreads();
    const int b = row0 >> 11, t0 = row0 & 2047;
    const int srow = tid >> 2, scb = (tid & 3) * 16;
#pragma unroll
    for (int i = 0; i < 2; i++) {
        *(bf16x8*)(Qb + (long)(row0 + srow) * 64 + scb + i * 8) =
            *(bf16x8*)(&Xs[0][srow * 72 + scb + i * 8]);
        *(bf16x8*)(Kb + (long)(row0 + srow) * 64 + scb + i * 8) =
            *(bf16x8*)(&Xs[1][srow * 72 + scb + i * 8]);
        *(bf16x8*)(Vtg + (long)(b * 64 + srow) * 2048 + t0 + scb + i * 8) =
            *(bf16x8*)(&Ws[0][srow * 72 + scb + i * 8]);
    }
}

// ---------------------------------------------------------------------------
// Kernel 2: flash attention (R8 verbatim: reg staging, XOR swizzle, single
// barrier/iter, PV lags S). 512 blocks x 256 thr, 32 k-iters. LDS 49152 B:
//   Qs/Ps0 @0 | KsA 2x8192 @8192 | VsA 2x8192 @24576 | Ps1 @40960
// Parity audit: K commit [kt+1], S reads [kt]; V commit [kt], PV reads
// [kt-1]; Ps write [kt], PV reads [kt-1] -- all barrier-separated.
// ---------------------------------------------------------------------------
__global__ __launch_bounds__(256) void flash_attn(const bf16* __restrict__ Qb,
                                                  const bf16* __restrict__ Kb,
                                                  const bf16* __restrict__ Vtg,
                                                  float* __restrict__ out) {
    __shared__ __align__(16) char smem[49152];
    bf16* Qs  = (bf16*)smem;                  // [64][64]; Ps0 overlays after hoist
    bf16* Ps0 = Qs;
    bf16* Ps1 = (bf16*)(smem + 40960);

    const int tid = threadIdx.x;
    const int wv = tid >> 6, lane = tid & 63, quad = lane >> 4, l16 = lane & 15;
    // XCD-aware swizzle: keep a batch's K/V resident in one XCD's L2.
    const int i0 = blockIdx.x;
    const int b = (i0 & 7) + 8 * ((i0 >> 3) >> 5);
    const int qt = (i0 >> 3) & 31;

    const bf16* Qg = Qb + (long)(b * 2048 + qt * 64) * 64;
    const bf16* Kg = Kb + (long)b * 2048 * 64;
    const bf16* Vg = Vtg + (long)b * 64 * 2048;

    const int srow = tid >> 2, scb = (tid & 3) * 16;
    // stage Q tile [64][64] (swizzled)
    *(bf16x8*)tp(Qs, srow, scb * 2)      = *(const bf16x8*)(Qg + srow * 64 + scb);
    *(bf16x8*)tp(Qs, srow, scb * 2 + 16) = *(const bf16x8*)(Qg + srow * 64 + scb + 8);

    // prologue loads: K[0] (commit now), K[1] and V[0] (regs for kt=0)
    bf16x8 k0[2], kp[2], vp[2];
#pragma unroll
    for (int i = 0; i < 2; i++) {
        k0[i] = *(const bf16x8*)(Kg + (long)srow * 64 + scb + i * 8);
        kp[i] = *(const bf16x8*)(Kg + (long)(64 + srow) * 64 + scb + i * 8);
        vp[i] = *(const bf16x8*)(Vg + (long)srow * 2048 + scb + i * 8);
    }
    bf16* Ks0 = (bf16*)(smem + 8192);
#pragma unroll
    for (int i = 0; i < 2; i++)
        *(bf16x8*)tp(Ks0, srow, scb * 2 + i * 16) = k0[i];

    f32x4 o[4], ol;
#pragma unroll
    for (int n = 0; n < 4; n++) o[n] = (f32x4){0.f, 0.f, 0.f, 0.f};
    ol = (f32x4){0.f, 0.f, 0.f, 0.f};

    __syncthreads();            // Qs + K[0] staged
    // hoist Q^T b-frags (loop-invariant)
    bf16x8 qb[4][2];
#pragma unroll
    for (int nt = 0; nt < 4; nt++)
#pragma unroll
        for (int kh = 0; kh < 2; kh++)
            qb[nt][kh] = *(bf16x8*)tp(Qs, nt * 16 + l16, kh * 64 + quad * 16);
    __syncthreads();            // all waves hoisted before Ps0 (=Qs) writes

    const bf16 one = (bf16)1.0f;
    const bf16x8 ones = {one, one, one, one, one, one, one, one};

#pragma unroll 2
    for (int kt = 0; kt < 32; kt++) {
        bf16* Kc = (bf16*)(smem + 8192  + (kt & 1) * 8192);        // S src: K[kt]
        bf16* Kn = (bf16*)(smem + 8192  + ((kt + 1) & 1) * 8192);  // commit K[kt+1]
        bf16* Vn = (bf16*)(smem + 24576 + (kt & 1) * 8192);        // commit V[kt]
        bf16* Vp = (bf16*)(smem + 24576 + ((kt + 1) & 1) * 8192);  // PV src: V[kt-1]
        bf16* Pw = (kt & 1) ? Ps1 : Ps0;                           // write Ps[kt]
        bf16* Pr = (kt & 1) ? Ps0 : Ps1;                           // read  Ps[kt-1]

        // commit prefetched tiles (regions not read this iteration)
        if (kt < 31) {
#pragma unroll
            for (int i = 0; i < 2; i++)
                *(bf16x8*)tp(Kn, srow, scb * 2 + i * 16) = kp[i];
        }
#pragma unroll
        for (int i = 0; i < 2; i++)
            *(bf16x8*)tp(Vn, srow, scb * 2 + i * 16) = vp[i];
        // issue next prefetches (loads stay in flight across the barrier)
        if (kt < 30) {
#pragma unroll
            for (int i = 0; i < 2; i++)
                kp[i] = *(const bf16x8*)(Kg + (long)((kt + 2) * 64 + srow) * 64 + scb + i * 8);
        }
        if (kt < 31) {
#pragma unroll
            for (int i = 0; i < 2; i++)
                vp[i] = *(const bf16x8*)(Vg + (long)srow * 2048 + (kt + 1) * 64 + scb + i * 8);
        }

        // S^T[kt] = K Q^T : wave's key subtile (m=wv), all 4 q-tiles
        f32x4 s[4];
#pragma unroll
        for (int nt = 0; nt < 4; nt++) s[nt] = (f32x4){0.f, 0.f, 0.f, 0.f};
#pragma unroll
        for (int kh = 0; kh < 2; kh++) {
            bf16x8 ka = *(bf16x8*)tp(Kc, wv * 16 + l16, kh * 64 + quad * 16);
#pragma unroll
            for (int nt = 0; nt < 4; nt++)
                s[nt] = __builtin_amdgcn_mfma_f32_16x16x32_bf16(ka, qb[nt][kh], s[nt], 0, 0, 0);
        }
        // p = exp2(s), pack 4 -> b64 store into Ps[kt]
#pragma unroll
        for (int nt = 0; nt < 4; nt++) {
            bf16x4 pp;
#pragma unroll
            for (int r = 0; r < 4; r++)
                pp[r] = (bf16)__builtin_amdgcn_exp2f(s[nt][r]);
            *(bf16x4*)tp(Pw, nt * 16 + l16, wv * 32 + quad * 8) = pp;
        }

        // O^T += V[kt-1]^T Ps[kt-1] : wave's q subtile (n=wv), 4 h-tiles + l
        if (kt) {
#pragma unroll
            for (int kh = 0; kh < 2; kh++) {
                bf16x8 pb = *(bf16x8*)tp(Pr, wv * 16 + l16, kh * 64 + quad * 16);
#pragma unroll
                for (int mt = 0; mt < 4; mt++) {
                    bf16x8 va = *(bf16x8*)tp(Vp, mt * 16 + l16, kh * 64 + quad * 16);
                    o[mt] = __builtin_amdgcn_mfma_f32_16x16x32_bf16(va, pb, o[mt], 0, 0, 0);
                }
                ol = __builtin_amdgcn_mfma_f32_16x16x32_bf16(ones, pb, ol, 0, 0, 0);
            }
        }
        __syncthreads();        // single barrier: publishes K[kt+1],V[kt],Ps[kt]
    }

    // peeled PV[31]: Ps[31] in Ps1, V[31] in VsA parity 1
    {
        bf16* Pr = Ps1;
        bf16* Vp = (bf16*)(smem + 24576 + 8192);
#pragma unroll
        for (int kh = 0; kh < 2; kh++) {
            bf16x8 pb = *(bf16x8*)tp(Pr, wv * 16 + l16, kh * 64 + quad * 16);
#pragma unroll
            for (int mt = 0; mt < 4; mt++) {
                bf16x8 va = *(bf16x8*)tp(Vp, mt * 16 + l16, kh * 64 + quad * 16);
                o[mt] = __builtin_amdgcn_mfma_f32_16x16x32_bf16(va, pb, o[mt], 0, 0, 0);
            }
            ol = __builtin_amdgcn_mfma_f32_16x16x32_bf16(ones, pb, ol, 0, 0, 0);
        }
    }

    // epilogue: every lane holds l(q) in ol[*]; normalize, transpose via LDS
    float inv = 1.0f / ol[0];
    __syncthreads();
    float* Om = (float*)(smem + 8192);        // [64][68] floats (17408 B)
#pragma unroll
    for (int mt = 0; mt < 4; mt++) {
        f32x4 ov;
#pragma unroll
        for (int r = 0; r < 4; r++) ov[r] = o[mt][r] * inv;
        *(f32x4*)(&Om[(wv * 16 + l16) * 68 + mt * 16 + quad * 4]) = ov;
    }
    __syncthreads();
    float* og = out + (long)(b * 2048 + qt * 64 + srow) * 64 + scb;
#pragma unroll
    for (int j = 0; j < 4; j++)
        *(float4*)(og + j * 4) = *(float4*)(&Om[srow * 68 + scb + j * 4]);
}

// ---------------------------------------------------------------------------
extern "C" void kernel_launch(void* const* d_in, const int* in_sizes, int n_in,
                              void* d_out, int out_size, void* d_ws, size_t ws_size,
                              hipStream_t stream) {
    const float* x  = (const float*)d_in[0];
    const float* Wq = (const float*)d_in[1];
    const float* Wk = (const float*)d_in[2];
    const float* Wv = (const float*)d_in[3];
    float* out = (float*)d_out;

    bf16* Qb  = (bf16*)d_ws;           // 32768*64
    bf16* Kb  = Qb + 2097152;
    bf16* Vtg = Kb + 2097152;          // [16][64][2048]
    bf16* Wt  = Vtg + 2097152;         // 6*192*64

    pack_w<<<288, 256, 0, stream>>>(Wq, Wk, Wv, Wt);
    qkv_proj<<<512, 256, 0, stream>>>(x, Wt, Qb, Kb, Vtg);
    flash_attn<<<512, 256, 0, stream>>>(Qb, Kb, Vtg, out);
}

// Round 8
// 124.641 us; speedup vs baseline: 1.0272x; 1.0272x over previous
//
#include <hip/hip_runtime.h>
#include <hip/hip_bf16.h>

// B=16, T=2048, C=384, H=64. out = softmax((x Wq)(x Wk)^T / sqrt(C)) (x Wv)
// ws (bf16): Qb[32768*64] | Kb[32768*64] | Vt[16][64][2048] | Wt[6*192*64]
// R11: qkv reverted to baseline (R7 column-split regressed: moved the 4x
// redundancy from B-frags to A-frags + branchy epilogue). flash: K-DIRECT
// fragment loads -- K's LDS round-trip existed only to redistribute rows
// (stage row tid>>2, frag needs row wv*16+l16); each lane now global-loads
// its own 16B fragment (K row-major), kept in regs, prefetched one full
// iteration ahead (~1700 cy >> L2 latency; K is L2-resident, XCD-matched).
// Deletes 8KB ds_write + 8KB ds_read per block-iter: LDS 144->112 KB/CU-iter
// (flash is LDS-throughput-bound at 85 B/cy). kf[kt&1] static via unroll 2.
// V/Ps stay in LDS (V-direct would 4x-duplicate L2 traffic; Ps is the
// cross-wave S->PV handoff). Flash LDS 49152 -> 32768 B.

typedef __bf16 bf16;
typedef __attribute__((ext_vector_type(8))) __bf16 bf16x8;
typedef __attribute__((ext_vector_type(4))) __bf16 bf16x4;
typedef __attribute__((ext_vector_type(4))) float f32x4;

#define SCALE_LOG2E (0.051031036307982884f * 1.4426950408889634f)

// swizzled element pointer into a [64][64] bf16 tile (128 B rows):
// byte = row*128 + (cbyte ^ ((row&7)<<4)); bijective, keeps 16B/8B alignment.
__device__ __forceinline__ bf16* tp(bf16* base, int row, int cbyte) {
    return (bf16*)((char*)base + row * 128 + (cbyte ^ ((row & 7) << 4)));
}

// ---------------------------------------------------------------------------
// Kernel 0: pack W^T, Wt[ck][h][c'] (c = ck*64+c', h in [0,192) = Wq|Wk|Wv).
// ---------------------------------------------------------------------------
__global__ void pack_w(const float* __restrict__ Wq, const float* __restrict__ Wk,
                       const float* __restrict__ Wv, bf16* __restrict__ Wt) {
    int idx = blockIdx.x * 256 + threadIdx.x;      // 0..73727
    int cc = idx & 63;
    int hh = (idx >> 6) % 192;
    int ck = idx / 12288;
    const float* W = (hh < 64) ? Wq : (hh < 128 ? Wk : Wv);
    Wt[idx] = (bf16)W[(ck * 64 + cc) * 64 + (hh & 63)];
}

// ---------------------------------------------------------------------------
// Kernel 1: QKV projection (baseline version, row-split waves).
// ---------------------------------------------------------------------------
__global__ __launch_bounds__(256) void qkv_proj(const float* __restrict__ x,
                                                const bf16* __restrict__ Wt,
                                                bf16* __restrict__ Qb,
                                                bf16* __restrict__ Kb,
                                                bf16* __restrict__ Vtg) {
    __shared__ __align__(16) bf16 Xs[2][64 * 72];
    __shared__ __align__(16) bf16 Ws[2][192 * 72];

    const int tid = threadIdx.x;
    const int wv = tid >> 6, lane = tid & 63, quad = lane >> 4, l16 = lane & 15;
    const int row0 = blockIdx.x * 64;

    f32x4 acc[12];
#pragma unroll
    for (int n = 0; n < 12; n++) acc[n] = (f32x4){0.f, 0.f, 0.f, 0.f};

    float4 xpre[4];
    bf16x8 wpre[6];
#pragma unroll
    for (int k = 0; k < 4; k++) {
        int g = tid + k * 256;
        xpre[k] = *(const float4*)(x + (long)(row0 + (g >> 4)) * 384 + (g & 15) * 4);
    }
#pragma unroll
    for (int k = 0; k < 6; k++)
        wpre[k] = *(const bf16x8*)(Wt + (tid + k * 256) * 8);

    for (int ck = 0; ck < 6; ck++) {
        bf16* Xc = Xs[ck & 1];
        bf16* Wc = Ws[ck & 1];
#pragma unroll
        for (int k = 0; k < 4; k++) {
            int g = tid + k * 256;
            float4 xv = xpre[k];
            *(bf16x4*)(&Xc[(g >> 4) * 72 + (g & 15) * 4]) =
                (bf16x4){(bf16)xv.x, (bf16)xv.y, (bf16)xv.z, (bf16)xv.w};
        }
#pragma unroll
        for (int k = 0; k < 6; k++) {
            int g = tid + k * 256;
            *(bf16x8*)(&Wc[(g >> 3) * 72 + (g & 7) * 8]) = wpre[k];
        }
        if (ck < 5) {
#pragma unroll
            for (int k = 0; k < 4; k++) {
                int g = tid + k * 256;
                xpre[k] = *(const float4*)(x + (long)(row0 + (g >> 4)) * 384 +
                                           (ck + 1) * 64 + (g & 15) * 4);
            }
#pragma unroll
            for (int k = 0; k < 6; k++)
                wpre[k] = *(const bf16x8*)(Wt + (ck + 1) * 12288 + (tid + k * 256) * 8);
        }
        __syncthreads();
#pragma unroll
        for (int kh = 0; kh < 2; kh++) {
            bf16x8 a = *(bf16x8*)(&Xc[(wv * 16 + l16) * 72 + kh * 32 + quad * 8]);
#pragma unroll
            for (int n = 0; n < 12; n++) {
                bf16x8 b = *(bf16x8*)(&Wc[(n * 16 + l16) * 72 + kh * 32 + quad * 8]);
                acc[n] = __builtin_amdgcn_mfma_f32_16x16x32_bf16(a, b, acc[n], 0, 0, 0);
            }
        }
    }

    __syncthreads();
    const int drow = wv * 16 + quad * 4;
#pragma unroll
    for (int n = 0; n < 4; n++) {
#pragma unroll
        for (int r = 0; r < 4; r++) {
            Xs[0][(drow + r) * 72 + n * 16 + l16] = (bf16)(acc[n][r] * SCALE_LOG2E);
            Xs[1][(drow + r) * 72 + n * 16 + l16] = (bf16)acc[n + 4][r];
            Ws[0][(n * 16 + l16) * 72 + drow + r] = (bf16)acc[n + 8][r];
        }
    }
    __syncthreads();
    const int b = row0 >> 11, t0 = row0 & 2047;
    const int srow = tid >> 2, scb = (tid & 3) * 16;
#pragma unroll
    for (int i = 0; i < 2; i++) {
        *(bf16x8*)(Qb + (long)(row0 + srow) * 64 + scb + i * 8) =
            *(bf16x8*)(&Xs[0][srow * 72 + scb + i * 8]);
        *(bf16x8*)(Kb + (long)(row0 + srow) * 64 + scb + i * 8) =
            *(bf16x8*)(&Xs[1][srow * 72 + scb + i * 8]);
        *(bf16x8*)(Vtg + (long)(b * 64 + srow) * 2048 + t0 + scb + i * 8) =
            *(bf16x8*)(&Ws[0][srow * 72 + scb + i * 8]);
    }
}

// ---------------------------------------------------------------------------
// Kernel 2: flash attention, 512 blocks x 256 thr (4 waves), 32 k-iters.
// Single barrier/iter (PV lags S by 1). K fragments loaded DIRECTLY from
// global into registers (no K LDS staging). V/Ps in XOR-swizzled LDS tiles.
// LDS 32768 B: Qs/Ps0 @0 | VsA 2x8192 @8192 | Ps1 @24576
//   Om [64][68] f32 overlays @8192 (epilogue only, after final barrier).
// Parity audit: V commit [kt&1], PV reads [(kt+1)&1]=V[kt-1] (opposite);
// Ps write [kt&1], PV reads [(kt-1)&1] (opposite); kf[kt&1] consumed at
// iter kt, kf[(kt+1)&1] loaded at iter kt (reg WAR handled by compiler).
// ---------------------------------------------------------------------------
__global__ __launch_bounds__(256) void flash_attn(const bf16* __restrict__ Qb,
                                                  const bf16* __restrict__ Kb,
                                                  const bf16* __restrict__ Vtg,
                                                  float* __restrict__ out) {
    __shared__ __align__(16) char smem[32768];
    bf16* Qs  = (bf16*)smem;                  // [64][64]; Ps0 overlays after hoist
    bf16* Ps0 = Qs;
    bf16* Ps1 = (bf16*)(smem + 24576);

    const int tid = threadIdx.x;
    const int wv = tid >> 6, lane = tid & 63, quad = lane >> 4, l16 = lane & 15;
    // XCD-aware swizzle: keep a batch's K/V resident in one XCD's L2.
    const int i0 = blockIdx.x;
    const int b = (i0 & 7) + 8 * ((i0 >> 3) >> 5);
    const int qt = (i0 >> 3) & 31;

    const bf16* Qg = Qb + (long)(b * 2048 + qt * 64) * 64;
    const bf16* Kg = Kb + (long)b * 2048 * 64;
    const bf16* Vg = Vtg + (long)b * 64 * 2048;

    const int srow = tid >> 2, scb = (tid & 3) * 16;
    // stage Q tile [64][64] (swizzled)
    *(bf16x8*)tp(Qs, srow, scb * 2)      = *(const bf16x8*)(Qg + srow * 64 + scb);
    *(bf16x8*)tp(Qs, srow, scb * 2 + 16) = *(const bf16x8*)(Qg + srow * 64 + scb + 8);

    // K fragment base for this lane: row wv*16+l16, col chunk quad*8 (+kh*32).
    // ka[j] = K[kt*64 + wv*16 + l16][kh*32 + quad*8 + j]
    const bf16* Kfb = Kg + (wv * 16 + l16) * 64 + quad * 8;

    // prologue: K frags for kt=0 into kf[0]; V[0] prefetch into regs
    bf16x8 kf[2][2];
#pragma unroll
    for (int kh = 0; kh < 2; kh++)
        kf[0][kh] = *(const bf16x8*)(Kfb + kh * 32);
    bf16x8 vp[2];
#pragma unroll
    for (int i = 0; i < 2; i++)
        vp[i] = *(const bf16x8*)(Vg + (long)srow * 2048 + scb + i * 8);

    f32x4 o[4], ol;
#pragma unroll
    for (int n = 0; n < 4; n++) o[n] = (f32x4){0.f, 0.f, 0.f, 0.f};
    ol = (f32x4){0.f, 0.f, 0.f, 0.f};

    __syncthreads();            // Qs staged
    // hoist Q^T b-frags (loop-invariant)
    bf16x8 qb[4][2];
#pragma unroll
    for (int nt = 0; nt < 4; nt++)
#pragma unroll
        for (int kh = 0; kh < 2; kh++)
            qb[nt][kh] = *(bf16x8*)tp(Qs, nt * 16 + l16, kh * 64 + quad * 16);
    __syncthreads();            // all waves hoisted before Ps0 (=Qs) writes

    const bf16 one = (bf16)1.0f;
    const bf16x8 ones = {one, one, one, one, one, one, one, one};

#pragma unroll 2
    for (int kt = 0; kt < 32; kt++) {
        bf16* Vn = (bf16*)(smem + 8192 + (kt & 1) * 8192);        // commit V[kt]
        bf16* Vp = (bf16*)(smem + 8192 + ((kt + 1) & 1) * 8192);  // PV src: V[kt-1]
        bf16* Pw = (kt & 1) ? Ps1 : Ps0;                          // write Ps[kt]
        bf16* Pr = (kt & 1) ? Ps0 : Ps1;                          // read  Ps[kt-1]

        // commit prefetched V tile (region not read this iteration)
#pragma unroll
        for (int i = 0; i < 2; i++)
            *(bf16x8*)tp(Vn, srow, scb * 2 + i * 16) = vp[i];
        // issue next prefetches (stay in flight across the barrier)
        if (kt < 31) {
#pragma unroll
            for (int kh = 0; kh < 2; kh++)
                kf[(kt + 1) & 1][kh] =
                    *(const bf16x8*)(Kfb + (long)(kt + 1) * 4096 + kh * 32);
#pragma unroll
            for (int i = 0; i < 2; i++)
                vp[i] = *(const bf16x8*)(Vg + (long)srow * 2048 + (kt + 1) * 64 + scb + i * 8);
        }

        // S^T[kt] = K Q^T : wave's key subtile (m=wv), all 4 q-tiles.
        // K frags come straight from registers (loaded last iteration).
        f32x4 s[4];
#pragma unroll
        for (int nt = 0; nt < 4; nt++) s[nt] = (f32x4){0.f, 0.f, 0.f, 0.f};
#pragma unroll
        for (int kh = 0; kh < 2; kh++) {
            bf16x8 ka = kf[kt & 1][kh];
#pragma unroll
            for (int nt = 0; nt < 4; nt++)
                s[nt] = __builtin_amdgcn_mfma_f32_16x16x32_bf16(ka, qb[nt][kh], s[nt], 0, 0, 0);
        }
        // p = exp2(s), pack 4 -> b64 store into Ps[kt]
#pragma unroll
        for (int nt = 0; nt < 4; nt++) {
            bf16x4 pp;
#pragma unroll
            for (int r = 0; r < 4; r++)
                pp[r] = (bf16)__builtin_amdgcn_exp2f(s[nt][r]);
            *(bf16x4*)tp(Pw, nt * 16 + l16, wv * 32 + quad * 8) = pp;
        }

        // O^T += V[kt-1]^T Ps[kt-1] : wave's q subtile (n=wv), 4 h-tiles + l
        if (kt) {
#pragma unroll
            for (int kh = 0; kh < 2; kh++) {
                bf16x8 pb = *(bf16x8*)tp(Pr, wv * 16 + l16, kh * 64 + quad * 16);
#pragma unroll
                for (int mt = 0; mt < 4; mt++) {
                    bf16x8 va = *(bf16x8*)tp(Vp, mt * 16 + l16, kh * 64 + quad * 16);
                    o[mt] = __builtin_amdgcn_mfma_f32_16x16x32_bf16(va, pb, o[mt], 0, 0, 0);
                }
                ol = __builtin_amdgcn_mfma_f32_16x16x32_bf16(ones, pb, ol, 0, 0, 0);
            }
        }
        __syncthreads();        // single barrier: publishes V[kt] and Ps[kt]
    }

    // peeled PV[31]: Ps[31] in Ps1, V[31] in VsA parity 1
    {
        bf16* Pr = Ps1;
        bf16* Vp = (bf16*)(smem + 8192 + 8192);
#pragma unroll
        for (int kh = 0; kh < 2; kh++) {
            bf16x8 pb = *(bf16x8*)tp(Pr, wv * 16 + l16, kh * 64 + quad * 16);
#pragma unroll
            for (int mt = 0; mt < 4; mt++) {
                bf16x8 va = *(bf16x8*)tp(Vp, mt * 16 + l16, kh * 64 + quad * 16);
                o[mt] = __builtin_amdgcn_mfma_f32_16x16x32_bf16(va, pb, o[mt], 0, 0, 0);
            }
            ol = __builtin_amdgcn_mfma_f32_16x16x32_bf16(ones, pb, ol, 0, 0, 0);
        }
    }

    // epilogue: every lane holds l(q) in ol[*]; normalize, transpose via LDS
    float inv = 1.0f / ol[0];
    __syncthreads();
    float* Om = (float*)(smem + 8192);        // [64][68] floats (17408 B)
#pragma unroll
    for (int mt = 0; mt < 4; mt++) {
        f32x4 ov;
#pragma unroll
        for (int r = 0; r < 4; r++) ov[r] = o[mt][r] * inv;
        *(f32x4*)(&Om[(wv * 16 + l16) * 68 + mt * 16 + quad * 4]) = ov;
    }
    __syncthreads();
    float* og = out + (long)(b * 2048 + qt * 64 + srow) * 64 + scb;
#pragma unroll
    for (int j = 0; j < 4; j++)
        *(float4*)(og + j * 4) = *(float4*)(&Om[srow * 68 + scb + j * 4]);
}

// ---------------------------------------------------------------------------
extern "C" void kernel_launch(void* const* d_in, const int* in_sizes, int n_in,
                              void* d_out, int out_size, void* d_ws, size_t ws_size,
                              hipStream_t stream) {
    const float* x  = (const float*)d_in[0];
    const float* Wq = (const float*)d_in[1];
    const float* Wk = (const float*)d_in[2];
    const float* Wv = (const float*)d_in[3];
    float* out = (float*)d_out;

    bf16* Qb  = (bf16*)d_ws;           // 32768*64
    bf16* Kb  = Qb + 2097152;
    bf16* Vtg = Kb + 2097152;          // [16][64][2048]
    bf16* Wt  = Vtg + 2097152;         // 6*192*64

    pack_w<<<288, 256, 0, stream>>>(Wq, Wk, Wv, Wt);
    qkv_proj<<<512, 256, 0, stream>>>(x, Wt, Qb, Kb, Vtg);
    flash_attn<<<512, 256, 0, stream>>>(Qb, Kb, Vtg, out);
}

// Round 9
// 120.747 us; speedup vs baseline: 1.0603x; 1.0323x over previous
//
#include <hip/hip_runtime.h>
#include <hip/hip_bf16.h>

// B=16, T=2048, C=384, H=64. out = softmax((x Wq)(x Wk)^T / sqrt(C)) (x Wv)
// ws (bf16): Qb[32768*64] | Kb[32768*64] | Vt[16][64][2048] | Wt[6*192*64]
// R12: flash wave-specialized, 512 thr (8 waves), grid 512 -> 16 waves/CU
// (4/SIMD, was 2/SIMD). R8 lesson: deleting 22% of LDS traffic gained only
// ~0.8us -> flash is latency/dependency-bound, not LDS-BW-bound. Same total
// MFMA/LDS ops, twice the waves each doing half: waves 0-3 (S-waves) own a
// key-subtile: K-direct frags, 8 S-MFMA, 16 exp2, Ps write, V staging;
// waves 4-7 (PV-waves) own a q-subtile: pure consumers (pb/va reads,
// 10 MFMA). S exp2 chains co-schedule against PV MFMA on each SIMD (m114);
// barrier drains hidden by 4x wave diversity. Single barrier/iter, PV lags
// S by 1 (parity audit unchanged from R8). LDS 32KB, 2 blocks/CU.

typedef __bf16 bf16;
typedef __attribute__((ext_vector_type(8))) __bf16 bf16x8;
typedef __attribute__((ext_vector_type(4))) __bf16 bf16x4;
typedef __attribute__((ext_vector_type(4))) float f32x4;

#define SCALE_LOG2E (0.051031036307982884f * 1.4426950408889634f)

// swizzled element pointer into a [64][64] bf16 tile (128 B rows):
// byte = row*128 + (cbyte ^ ((row&7)<<4)); bijective, keeps 16B/8B alignment.
__device__ __forceinline__ bf16* tp(bf16* base, int row, int cbyte) {
    return (bf16*)((char*)base + row * 128 + (cbyte ^ ((row & 7) << 4)));
}

// ---------------------------------------------------------------------------
// Kernel 0: pack W^T, Wt[ck][h][c'] (c = ck*64+c', h in [0,192) = Wq|Wk|Wv).
// ---------------------------------------------------------------------------
__global__ void pack_w(const float* __restrict__ Wq, const float* __restrict__ Wk,
                       const float* __restrict__ Wv, bf16* __restrict__ Wt) {
    int idx = blockIdx.x * 256 + threadIdx.x;      // 0..73727
    int cc = idx & 63;
    int hh = (idx >> 6) % 192;
    int ck = idx / 12288;
    const float* W = (hh < 64) ? Wq : (hh < 128 ? Wk : Wv);
    Wt[idx] = (bf16)W[(ck * 64 + cc) * 64 + (hh & 63)];
}

// ---------------------------------------------------------------------------
// Kernel 1: QKV projection (baseline version, row-split waves).
// ---------------------------------------------------------------------------
__global__ __launch_bounds__(256) void qkv_proj(const float* __restrict__ x,
                                                const bf16* __restrict__ Wt,
                                                bf16* __restrict__ Qb,
                                                bf16* __restrict__ Kb,
                                                bf16* __restrict__ Vtg) {
    __shared__ __align__(16) bf16 Xs[2][64 * 72];
    __shared__ __align__(16) bf16 Ws[2][192 * 72];

    const int tid = threadIdx.x;
    const int wv = tid >> 6, lane = tid & 63, quad = lane >> 4, l16 = lane & 15;
    const int row0 = blockIdx.x * 64;

    f32x4 acc[12];
#pragma unroll
    for (int n = 0; n < 12; n++) acc[n] = (f32x4){0.f, 0.f, 0.f, 0.f};

    float4 xpre[4];
    bf16x8 wpre[6];
#pragma unroll
    for (int k = 0; k < 4; k++) {
        int g = tid + k * 256;
        xpre[k] = *(const float4*)(x + (long)(row0 + (g >> 4)) * 384 + (g & 15) * 4);
    }
#pragma unroll
    for (int k = 0; k < 6; k++)
        wpre[k] = *(const bf16x8*)(Wt + (tid + k * 256) * 8);

    for (int ck = 0; ck < 6; ck++) {
        bf16* Xc = Xs[ck & 1];
        bf16* Wc = Ws[ck & 1];
#pragma unroll
        for (int k = 0; k < 4; k++) {
            int g = tid + k * 256;
            float4 xv = xpre[k];
            *(bf16x4*)(&Xc[(g >> 4) * 72 + (g & 15) * 4]) =
                (bf16x4){(bf16)xv.x, (bf16)xv.y, (bf16)xv.z, (bf16)xv.w};
        }
#pragma unroll
        for (int k = 0; k < 6; k++) {
            int g = tid + k * 256;
            *(bf16x8*)(&Wc[(g >> 3) * 72 + (g & 7) * 8]) = wpre[k];
        }
        if (ck < 5) {
#pragma unroll
            for (int k = 0; k < 4; k++) {
                int g = tid + k * 256;
                xpre[k] = *(const float4*)(x + (long)(row0 + (g >> 4)) * 384 +
                                           (ck + 1) * 64 + (g & 15) * 4);
            }
#pragma unroll
            for (int k = 0; k < 6; k++)
                wpre[k] = *(const bf16x8*)(Wt + (ck + 1) * 12288 + (tid + k * 256) * 8);
        }
        __syncthreads();
#pragma unroll
        for (int kh = 0; kh < 2; kh++) {
            bf16x8 a = *(bf16x8*)(&Xc[(wv * 16 + l16) * 72 + kh * 32 + quad * 8]);
#pragma unroll
            for (int n = 0; n < 12; n++) {
                bf16x8 b = *(bf16x8*)(&Wc[(n * 16 + l16) * 72 + kh * 32 + quad * 8]);
                acc[n] = __builtin_amdgcn_mfma_f32_16x16x32_bf16(a, b, acc[n], 0, 0, 0);
            }
        }
    }

    __syncthreads();
    const int drow = wv * 16 + quad * 4;
#pragma unroll
    for (int n = 0; n < 4; n++) {
#pragma unroll
        for (int r = 0; r < 4; r++) {
            Xs[0][(drow + r) * 72 + n * 16 + l16] = (bf16)(acc[n][r] * SCALE_LOG2E);
            Xs[1][(drow + r) * 72 + n * 16 + l16] = (bf16)acc[n + 4][r];
            Ws[0][(n * 16 + l16) * 72 + drow + r] = (bf16)acc[n + 8][r];
        }
    }
    __syncthreads();
    const int b = row0 >> 11, t0 = row0 & 2047;
    const int srow = tid >> 2, scb = (tid & 3) * 16;
#pragma unroll
    for (int i = 0; i < 2; i++) {
        *(bf16x8*)(Qb + (long)(row0 + srow) * 64 + scb + i * 8) =
            *(bf16x8*)(&Xs[0][srow * 72 + scb + i * 8]);
        *(bf16x8*)(Kb + (long)(row0 + srow) * 64 + scb + i * 8) =
            *(bf16x8*)(&Xs[1][srow * 72 + scb + i * 8]);
        *(bf16x8*)(Vtg + (long)(b * 64 + srow) * 2048 + t0 + scb + i * 8) =
            *(bf16x8*)(&Ws[0][srow * 72 + scb + i * 8]);
    }
}

// ---------------------------------------------------------------------------
// Kernel 2: flash attention, 512 blocks x 512 thr (8 waves), 32 k-iters.
// Waves 0-3 (S): key-subtile wv; K-direct frags; exp2; Ps write; V staging.
// Waves 4-7 (PV): q-subtile wv-4; pb/va LDS reads; O/l accumulate.
// LDS 32768 B: Qs/Ps0 @0 | VsA 2x8192 @8192 | Ps1 @24576
//   Om [64][68] f32 overlays @8192 (epilogue only, after final barrier).
// Parity: V commit [kt&1] (S-waves), PV reads [(kt+1)&1]=V[kt-1];
// Ps write [kt&1] (S), PV reads [(kt-1)&1]; kf reg-dbuf under unroll 2.
// ---------------------------------------------------------------------------
__global__ __launch_bounds__(512) void flash_attn(const bf16* __restrict__ Qb,
                                                  const bf16* __restrict__ Kb,
                                                  const bf16* __restrict__ Vtg,
                                                  float* __restrict__ out) {
    __shared__ __align__(16) char smem[32768];
    bf16* Qs  = (bf16*)smem;                  // [64][64]; Ps0 overlays after hoist
    bf16* Ps0 = Qs;
    bf16* Ps1 = (bf16*)(smem + 24576);

    const int tid = threadIdx.x;
    const int wv = tid >> 6, lane = tid & 63, quad = lane >> 4, l16 = lane & 15;
    const bool sw = (wv < 4);                 // S/staging waves
    const int pq = wv - 4;                    // PV wave's q-tile
    // XCD-aware swizzle: keep a batch's K/V resident in one XCD's L2.
    const int i0 = blockIdx.x;
    const int b = (i0 & 7) + 8 * ((i0 >> 3) >> 5);
    const int qt = (i0 >> 3) & 31;

    const bf16* Qg = Qb + (long)(b * 2048 + qt * 64) * 64;
    const bf16* Kg = Kb + (long)b * 2048 * 64;
    const bf16* Vg = Vtg + (long)b * 64 * 2048;

    // stage Q tile [64][64] (swizzled): 512 thr x 16B
    const int qrow = tid >> 3, qcb = (tid & 7) * 16;
    *(bf16x8*)tp(Qs, qrow, qcb) = *(const bf16x8*)(Qg + qrow * 64 + (qcb >> 1));

    // V staging geometry (S-waves, tid<256): 256 lanes x 32B
    const int vrow = tid >> 2, vcb = (tid & 3) * 32;
    // K fragment base (S-waves): ka[j]=K[kt*64+wv*16+l16][kh*32+quad*8+j]
    const bf16* Kfb = Kg + (wv * 16 + l16) * 64 + quad * 8;

    bf16x8 kf[2][2], vp[2];
    if (sw) {
        kf[0][0] = *(const bf16x8*)(Kfb);
        kf[0][1] = *(const bf16x8*)(Kfb + 32);
        vp[0] = *(const bf16x8*)(Vg + (long)vrow * 2048 + (vcb >> 1));
        vp[1] = *(const bf16x8*)(Vg + (long)vrow * 2048 + (vcb >> 1) + 8);
    }

    f32x4 o[4], ol;
#pragma unroll
    for (int n = 0; n < 4; n++) o[n] = (f32x4){0.f, 0.f, 0.f, 0.f};
    ol = (f32x4){0.f, 0.f, 0.f, 0.f};

    __syncthreads();            // Qs staged
    // hoist Q^T b-frags (S-waves only; loop-invariant)
    bf16x8 qb[4][2];
    if (sw) {
#pragma unroll
        for (int nt = 0; nt < 4; nt++)
#pragma unroll
            for (int kh = 0; kh < 2; kh++)
                qb[nt][kh] = *(bf16x8*)tp(Qs, nt * 16 + l16, kh * 64 + quad * 16);
    }
    __syncthreads();            // hoist done before Ps0 (=Qs) writes

    const bf16 one = (bf16)1.0f;
    const bf16x8 ones = {one, one, one, one, one, one, one, one};

#pragma unroll 2
    for (int kt = 0; kt < 32; kt++) {
        bf16* Vn = (bf16*)(smem + 8192 + (kt & 1) * 8192);        // commit V[kt]
        bf16* Vp = (bf16*)(smem + 8192 + ((kt + 1) & 1) * 8192);  // PV src: V[kt-1]
        bf16* Pw = (kt & 1) ? Ps1 : Ps0;                          // write Ps[kt]
        bf16* Pr = (kt & 1) ? Ps0 : Ps1;                          // read  Ps[kt-1]

        if (sw) {
            // commit prefetched V tile (region not read this iteration)
            *(bf16x8*)tp(Vn, vrow, vcb)      = vp[0];
            *(bf16x8*)tp(Vn, vrow, vcb + 16) = vp[1];
            // issue next prefetches (stay in flight across the barrier)
            if (kt < 31) {
                kf[(kt + 1) & 1][0] = *(const bf16x8*)(Kfb + (long)(kt + 1) * 4096);
                kf[(kt + 1) & 1][1] = *(const bf16x8*)(Kfb + (long)(kt + 1) * 4096 + 32);
                vp[0] = *(const bf16x8*)(Vg + (long)vrow * 2048 + (kt + 1) * 64 + (vcb >> 1));
                vp[1] = *(const bf16x8*)(Vg + (long)vrow * 2048 + (kt + 1) * 64 + (vcb >> 1) + 8);
            }
            // S^T[kt] = K Q^T : this wave's key subtile (m=wv), all 4 q-tiles
            f32x4 s[4];
#pragma unroll
            for (int nt = 0; nt < 4; nt++) s[nt] = (f32x4){0.f, 0.f, 0.f, 0.f};
#pragma unroll
            for (int kh = 0; kh < 2; kh++) {
                bf16x8 ka = kf[kt & 1][kh];
#pragma unroll
                for (int nt = 0; nt < 4; nt++)
                    s[nt] = __builtin_amdgcn_mfma_f32_16x16x32_bf16(ka, qb[nt][kh], s[nt], 0, 0, 0);
            }
            // p = exp2(s), pack 4 -> b64 store into Ps[kt]
#pragma unroll
            for (int nt = 0; nt < 4; nt++) {
                bf16x4 pp;
#pragma unroll
                for (int r = 0; r < 4; r++)
                    pp[r] = (bf16)__builtin_amdgcn_exp2f(s[nt][r]);
                *(bf16x4*)tp(Pw, nt * 16 + l16, wv * 32 + quad * 8) = pp;
            }
        } else if (kt) {
            // O^T += V[kt-1]^T Ps[kt-1] : this wave's q subtile (n=pq)
#pragma unroll
            for (int kh = 0; kh < 2; kh++) {
                bf16x8 pb = *(bf16x8*)tp(Pr, pq * 16 + l16, kh * 64 + quad * 16);
#pragma unroll
                for (int mt = 0; mt < 4; mt++) {
                    bf16x8 va = *(bf16x8*)tp(Vp, mt * 16 + l16, kh * 64 + quad * 16);
                    o[mt] = __builtin_amdgcn_mfma_f32_16x16x32_bf16(va, pb, o[mt], 0, 0, 0);
                }
                ol = __builtin_amdgcn_mfma_f32_16x16x32_bf16(ones, pb, ol, 0, 0, 0);
            }
        }
        __syncthreads();        // single barrier: publishes V[kt] and Ps[kt]
    }

    // peeled PV[31]: Ps[31] in Ps1, V[31] in parity-1 buffer
    if (!sw) {
        bf16* Pr = Ps1;
        bf16* Vp = (bf16*)(smem + 16384);
#pragma unroll
        for (int kh = 0; kh < 2; kh++) {
            bf16x8 pb = *(bf16x8*)tp(Pr, pq * 16 + l16, kh * 64 + quad * 16);
#pragma unroll
            for (int mt = 0; mt < 4; mt++) {
                bf16x8 va = *(bf16x8*)tp(Vp, mt * 16 + l16, kh * 64 + quad * 16);
                o[mt] = __builtin_amdgcn_mfma_f32_16x16x32_bf16(va, pb, o[mt], 0, 0, 0);
            }
            ol = __builtin_amdgcn_mfma_f32_16x16x32_bf16(ones, pb, ol, 0, 0, 0);
        }
    }

    // epilogue: PV lanes hold l(q) in ol[*]; normalize, transpose via LDS
    float inv = 1.0f / ol[0];
    __syncthreads();            // last loop reads done before Om overlay
    float* Om = (float*)(smem + 8192);        // [64][68] floats (17408 B)
    if (!sw) {
#pragma unroll
        for (int mt = 0; mt < 4; mt++) {
            f32x4 ov;
#pragma unroll
            for (int r = 0; r < 4; r++) ov[r] = o[mt][r] * inv;
            *(f32x4*)(&Om[(pq * 16 + l16) * 68 + mt * 16 + quad * 4]) = ov;
        }
    }
    __syncthreads();
    const int orow = tid >> 3, ocf = (tid & 7) * 8;
    float* og = out + (long)(b * 2048 + qt * 64 + orow) * 64 + ocf;
#pragma unroll
    for (int j = 0; j < 2; j++)
        *(float4*)(og + j * 4) = *(float4*)(&Om[orow * 68 + ocf + j * 4]);
}

// ---------------------------------------------------------------------------
extern "C" void kernel_launch(void* const* d_in, const int* in_sizes, int n_in,
                              void* d_out, int out_size, void* d_ws, size_t ws_size,
                              hipStream_t stream) {
    const float* x  = (const float*)d_in[0];
    const float* Wq = (const float*)d_in[1];
    const float* Wk = (const float*)d_in[2];
    const float* Wv = (const float*)d_in[3];
    float* out = (float*)d_out;

    bf16* Qb  = (bf16*)d_ws;           // 32768*64
    bf16* Kb  = Qb + 2097152;
    bf16* Vtg = Kb + 2097152;          // [16][64][2048]
    bf16* Wt  = Vtg + 2097152;         // 6*192*64

    pack_w<<<288, 256, 0, stream>>>(Wq, Wk, Wv, Wt);
    qkv_proj<<<512, 256, 0, stream>>>(x, Wt, Qb, Kb, Vtg);
    flash_attn<<<512, 512, 0, stream>>>(Qb, Kb, Vtg, out);
}

// Round 10
// 120.599 us; speedup vs baseline: 1.0616x; 1.0012x over previous
//
#include <hip/hip_runtime.h>
#include <hip/hip_bf16.h>

// B=16, T=2048, C=384, H=64. out = softmax((x Wq)(x Wk)^T / sqrt(C)) (x Wv)
// ws (bf16): Qb[32768*64] | Kb[32768*64] | Vt[16][64][2048] | Wt[6*192*64]
// R13: (a) qkv at 8 waves/block (512 thr): wave (rg,cg) owns rows rg*32+32
// x n-tiles cg*3+3 -> 16 waves/CU (4/SIMD, was 2) for a memory-latency-
// bound kernel (R9 proved the same lever on flash). Same total MFMA/LDS
// ops; per-thread staging halves. (b) flash: s_setprio(1) around S and PV
// MFMA clusters -- T5's role-split precondition is satisfied since R12
// (S-waves vs PV-waves at different phases on each SIMD; m218b/m191).

typedef __bf16 bf16;
typedef __attribute__((ext_vector_type(8))) __bf16 bf16x8;
typedef __attribute__((ext_vector_type(4))) __bf16 bf16x4;
typedef __attribute__((ext_vector_type(4))) float f32x4;

#define SCALE_LOG2E (0.051031036307982884f * 1.4426950408889634f)

// swizzled element pointer into a [64][64] bf16 tile (128 B rows):
// byte = row*128 + (cbyte ^ ((row&7)<<4)); bijective, keeps 16B/8B alignment.
__device__ __forceinline__ bf16* tp(bf16* base, int row, int cbyte) {
    return (bf16*)((char*)base + row * 128 + (cbyte ^ ((row & 7) << 4)));
}

// ---------------------------------------------------------------------------
// Kernel 0: pack W^T, Wt[ck][h][c'] (c = ck*64+c', h in [0,192) = Wq|Wk|Wv).
// ---------------------------------------------------------------------------
__global__ void pack_w(const float* __restrict__ Wq, const float* __restrict__ Wk,
                       const float* __restrict__ Wv, bf16* __restrict__ Wt) {
    int idx = blockIdx.x * 256 + threadIdx.x;      // 0..73727
    int cc = idx & 63;
    int hh = (idx >> 6) % 192;
    int ck = idx / 12288;
    const float* W = (hh < 64) ? Wq : (hh < 128 ? Wk : Wv);
    Wt[idx] = (bf16)W[(ck * 64 + cc) * 64 + (hh & 63)];
}

// ---------------------------------------------------------------------------
// Kernel 1: QKV projection. 64 rows x 192 cols per block, 512 thr (8 waves).
// Wave wv=(rg<<2)|cg: rows rg*32+rt*16 (rt<2), n-tiles cg*3+j (j<3).
// Per wave per chunk: 2kh x (3 b + 2 a) = 10 LDS reads, 12 MFMA. Total
// block ops unchanged vs 4-wave baseline; occupancy 2->4 waves/SIMD.
// ---------------------------------------------------------------------------
__global__ __launch_bounds__(512) void qkv_proj(const float* __restrict__ x,
                                                const bf16* __restrict__ Wt,
                                                bf16* __restrict__ Qb,
                                                bf16* __restrict__ Kb,
                                                bf16* __restrict__ Vtg) {
    __shared__ __align__(16) bf16 Xs[2][64 * 72];
    __shared__ __align__(16) bf16 Ws[2][192 * 72];

    const int tid = threadIdx.x;
    const int wv = tid >> 6, lane = tid & 63, quad = lane >> 4, l16 = lane & 15;
    const int rg = wv >> 2, cg = wv & 3;
    const int row0 = blockIdx.x * 64;

    f32x4 acc[6];                                  // [rt][j] -> acc[rt*3+j]
#pragma unroll
    for (int n = 0; n < 6; n++) acc[n] = (f32x4){0.f, 0.f, 0.f, 0.f};

    float4 xpre[2];
    bf16x8 wpre[3];
#pragma unroll
    for (int k = 0; k < 2; k++) {
        int g = tid + k * 512;
        xpre[k] = *(const float4*)(x + (long)(row0 + (g >> 4)) * 384 + (g & 15) * 4);
    }
#pragma unroll
    for (int k = 0; k < 3; k++)
        wpre[k] = *(const bf16x8*)(Wt + (tid + k * 512) * 8);

    for (int ck = 0; ck < 6; ck++) {
        bf16* Xc = Xs[ck & 1];
        bf16* Wc = Ws[ck & 1];
#pragma unroll
        for (int k = 0; k < 2; k++) {
            int g = tid + k * 512;
            float4 xv = xpre[k];
            *(bf16x4*)(&Xc[(g >> 4) * 72 + (g & 15) * 4]) =
                (bf16x4){(bf16)xv.x, (bf16)xv.y, (bf16)xv.z, (bf16)xv.w};
        }
#pragma unroll
        for (int k = 0; k < 3; k++) {
            int g = tid + k * 512;
            *(bf16x8*)(&Wc[(g >> 3) * 72 + (g & 7) * 8]) = wpre[k];
        }
        if (ck < 5) {
#pragma unroll
            for (int k = 0; k < 2; k++) {
                int g = tid + k * 512;
                xpre[k] = *(const float4*)(x + (long)(row0 + (g >> 4)) * 384 +
                                           (ck + 1) * 64 + (g & 15) * 4);
            }
#pragma unroll
            for (int k = 0; k < 3; k++)
                wpre[k] = *(const bf16x8*)(Wt + (ck + 1) * 12288 + (tid + k * 512) * 8);
        }
        __syncthreads();
#pragma unroll
        for (int kh = 0; kh < 2; kh++) {
            bf16x8 bb[3];
#pragma unroll
            for (int j = 0; j < 3; j++)
                bb[j] = *(bf16x8*)(&Wc[((cg * 3 + j) * 16 + l16) * 72 + kh * 32 + quad * 8]);
#pragma unroll
            for (int rt = 0; rt < 2; rt++) {
                bf16x8 a = *(bf16x8*)(&Xc[(rg * 32 + rt * 16 + l16) * 72 + kh * 32 + quad * 8]);
#pragma unroll
                for (int j = 0; j < 3; j++)
                    acc[rt * 3 + j] = __builtin_amdgcn_mfma_f32_16x16x32_bf16(
                        a, bb[j], acc[rt * 3 + j], 0, 0, 0);
            }
        }
    }

    // epilogue: scatter acc (n = cg*3+j wave-uniform) into staging buffers
    __syncthreads();
#pragma unroll
    for (int rt = 0; rt < 2; rt++) {
#pragma unroll
        for (int j = 0; j < 3; j++) {
            const int n = cg * 3 + j;
            const int drow = rg * 32 + rt * 16 + quad * 4;
#pragma unroll
            for (int r = 0; r < 4; r++) {
                float v = acc[rt * 3 + j][r];
                if (n < 4)
                    Xs[0][(drow + r) * 72 + n * 16 + l16] = (bf16)(v * SCALE_LOG2E);
                else if (n < 8)
                    Xs[1][(drow + r) * 72 + (n - 4) * 16 + l16] = (bf16)v;
                else
                    Ws[0][((n - 8) * 16 + l16) * 72 + drow + r] = (bf16)v;
            }
        }
    }
    __syncthreads();
    const int b = row0 >> 11, t0 = row0 & 2047;
    const int srow = tid >> 3, scb = (tid & 7) * 8;
    *(bf16x8*)(Qb + (long)(row0 + srow) * 64 + scb) =
        *(bf16x8*)(&Xs[0][srow * 72 + scb]);
    *(bf16x8*)(Kb + (long)(row0 + srow) * 64 + scb) =
        *(bf16x8*)(&Xs[1][srow * 72 + scb]);
    *(bf16x8*)(Vtg + (long)(b * 64 + srow) * 2048 + t0 + scb) =
        *(bf16x8*)(&Ws[0][srow * 72 + scb]);
}

// ---------------------------------------------------------------------------
// Kernel 2: flash attention, 512 blocks x 512 thr (8 waves), 32 k-iters.
// Waves 0-3 (S): key-subtile wv; K-direct frags; exp2; Ps write; V staging.
// Waves 4-7 (PV): q-subtile wv-4; pb/va LDS reads; O/l accumulate.
// s_setprio(1) around both MFMA clusters (T5; role-split satisfied).
// LDS 32768 B: Qs/Ps0 @0 | VsA 2x8192 @8192 | Ps1 @24576
//   Om [64][68] f32 overlays @8192 (epilogue only, after final barrier).
// Parity: V commit [kt&1] (S), PV reads [(kt+1)&1]=V[kt-1]; Ps write
// [kt&1] (S), PV reads [(kt-1)&1]; kf reg-dbuf under unroll 2.
// ---------------------------------------------------------------------------
__global__ __launch_bounds__(512) void flash_attn(const bf16* __restrict__ Qb,
                                                  const bf16* __restrict__ Kb,
                                                  const bf16* __restrict__ Vtg,
                                                  float* __restrict__ out) {
    __shared__ __align__(16) char smem[32768];
    bf16* Qs  = (bf16*)smem;                  // [64][64]; Ps0 overlays after hoist
    bf16* Ps0 = Qs;
    bf16* Ps1 = (bf16*)(smem + 24576);

    const int tid = threadIdx.x;
    const int wv = tid >> 6, lane = tid & 63, quad = lane >> 4, l16 = lane & 15;
    const bool sw = (wv < 4);                 // S/staging waves
    const int pq = wv - 4;                    // PV wave's q-tile
    // XCD-aware swizzle: keep a batch's K/V resident in one XCD's L2.
    const int i0 = blockIdx.x;
    const int b = (i0 & 7) + 8 * ((i0 >> 3) >> 5);
    const int qt = (i0 >> 3) & 31;

    const bf16* Qg = Qb + (long)(b * 2048 + qt * 64) * 64;
    const bf16* Kg = Kb + (long)b * 2048 * 64;
    const bf16* Vg = Vtg + (long)b * 64 * 2048;

    // stage Q tile [64][64] (swizzled): 512 thr x 16B
    const int qrow = tid >> 3, qcb = (tid & 7) * 16;
    *(bf16x8*)tp(Qs, qrow, qcb) = *(const bf16x8*)(Qg + qrow * 64 + (qcb >> 1));

    // V staging geometry (S-waves, tid<256): 256 lanes x 32B
    const int vrow = tid >> 2, vcb = (tid & 3) * 32;
    // K fragment base (S-waves): ka[j]=K[kt*64+wv*16+l16][kh*32+quad*8+j]
    const bf16* Kfb = Kg + (wv * 16 + l16) * 64 + quad * 8;

    bf16x8 kf[2][2], vp[2];
    if (sw) {
        kf[0][0] = *(const bf16x8*)(Kfb);
        kf[0][1] = *(const bf16x8*)(Kfb + 32);
        vp[0] = *(const bf16x8*)(Vg + (long)vrow * 2048 + (vcb >> 1));
        vp[1] = *(const bf16x8*)(Vg + (long)vrow * 2048 + (vcb >> 1) + 8);
    }

    f32x4 o[4], ol;
#pragma unroll
    for (int n = 0; n < 4; n++) o[n] = (f32x4){0.f, 0.f, 0.f, 0.f};
    ol = (f32x4){0.f, 0.f, 0.f, 0.f};

    __syncthreads();            // Qs staged
    // hoist Q^T b-frags (S-waves only; loop-invariant)
    bf16x8 qb[4][2];
    if (sw) {
#pragma unroll
        for (int nt = 0; nt < 4; nt++)
#pragma unroll
            for (int kh = 0; kh < 2; kh++)
                qb[nt][kh] = *(bf16x8*)tp(Qs, nt * 16 + l16, kh * 64 + quad * 16);
    }
    __syncthreads();            // hoist done before Ps0 (=Qs) writes

    const bf16 one = (bf16)1.0f;
    const bf16x8 ones = {one, one, one, one, one, one, one, one};

#pragma unroll 2
    for (int kt = 0; kt < 32; kt++) {
        bf16* Vn = (bf16*)(smem + 8192 + (kt & 1) * 8192);        // commit V[kt]
        bf16* Vp = (bf16*)(smem + 8192 + ((kt + 1) & 1) * 8192);  // PV src: V[kt-1]
        bf16* Pw = (kt & 1) ? Ps1 : Ps0;                          // write Ps[kt]
        bf16* Pr = (kt & 1) ? Ps0 : Ps1;                          // read  Ps[kt-1]

        if (sw) {
            // commit prefetched V tile (region not read this iteration)
            *(bf16x8*)tp(Vn, vrow, vcb)      = vp[0];
            *(bf16x8*)tp(Vn, vrow, vcb + 16) = vp[1];
            // issue next prefetches (stay in flight across the barrier)
            if (kt < 31) {
                kf[(kt + 1) & 1][0] = *(const bf16x8*)(Kfb + (long)(kt + 1) * 4096);
                kf[(kt + 1) & 1][1] = *(const bf16x8*)(Kfb + (long)(kt + 1) * 4096 + 32);
                vp[0] = *(const bf16x8*)(Vg + (long)vrow * 2048 + (kt + 1) * 64 + (vcb >> 1));
                vp[1] = *(const bf16x8*)(Vg + (long)vrow * 2048 + (kt + 1) * 64 + (vcb >> 1) + 8);
            }
            // S^T[kt] = K Q^T : this wave's key subtile (m=wv), all 4 q-tiles
            f32x4 s[4];
#pragma unroll
            for (int nt = 0; nt < 4; nt++) s[nt] = (f32x4){0.f, 0.f, 0.f, 0.f};
            __builtin_amdgcn_s_setprio(1);
#pragma unroll
            for (int kh = 0; kh < 2; kh++) {
                bf16x8 ka = kf[kt & 1][kh];
#pragma unroll
                for (int nt = 0; nt < 4; nt++)
                    s[nt] = __builtin_amdgcn_mfma_f32_16x16x32_bf16(ka, qb[nt][kh], s[nt], 0, 0, 0);
            }
            __builtin_amdgcn_s_setprio(0);
            // p = exp2(s), pack 4 -> b64 store into Ps[kt]
#pragma unroll
            for (int nt = 0; nt < 4; nt++) {
                bf16x4 pp;
#pragma unroll
                for (int r = 0; r < 4; r++)
                    pp[r] = (bf16)__builtin_amdgcn_exp2f(s[nt][r]);
                *(bf16x4*)tp(Pw, nt * 16 + l16, wv * 32 + quad * 8) = pp;
            }
        } else if (kt) {
            // O^T += V[kt-1]^T Ps[kt-1] : this wave's q subtile (n=pq)
            __builtin_amdgcn_s_setprio(1);
#pragma unroll
            for (int kh = 0; kh < 2; kh++) {
                bf16x8 pb = *(bf16x8*)tp(Pr, pq * 16 + l16, kh * 64 + quad * 16);
#pragma unroll
                for (int mt = 0; mt < 4; mt++) {
                    bf16x8 va = *(bf16x8*)tp(Vp, mt * 16 + l16, kh * 64 + quad * 16);
                    o[mt] = __builtin_amdgcn_mfma_f32_16x16x32_bf16(va, pb, o[mt], 0, 0, 0);
                }
                ol = __builtin_amdgcn_mfma_f32_16x16x32_bf16(ones, pb, ol, 0, 0, 0);
            }
            __builtin_amdgcn_s_setprio(0);
        }
        __syncthreads();        // single barrier: publishes V[kt] and Ps[kt]
    }

    // peeled PV[31]: Ps[31] in Ps1, V[31] in parity-1 buffer
    if (!sw) {
        bf16* Pr = Ps1;
        bf16* Vp = (bf16*)(smem + 16384);
#pragma unroll
        for (int kh = 0; kh < 2; kh++) {
            bf16x8 pb = *(bf16x8*)tp(Pr, pq * 16 + l16, kh * 64 + quad * 16);
#pragma unroll
            for (int mt = 0; mt < 4; mt++) {
                bf16x8 va = *(bf16x8*)tp(Vp, mt * 16 + l16, kh * 64 + quad * 16);
                o[mt] = __builtin_amdgcn_mfma_f32_16x16x32_bf16(va, pb, o[mt], 0, 0, 0);
            }
            ol = __builtin_amdgcn_mfma_f32_16x16x32_bf16(ones, pb, ol, 0, 0, 0);
        }
    }

    // epilogue: PV lanes hold l(q) in ol[*]; normalize, transpose via LDS
    float inv = 1.0f / ol[0];
    __syncthreads();            // last loop reads done before Om overlay
    float* Om = (float*)(smem + 8192);        // [64][68] floats (17408 B)
    if (!sw) {
#pragma unroll
        for (int mt = 0; mt < 4; mt++) {
            f32x4 ov;
#pragma unroll
            for (int r = 0; r < 4; r++) ov[r] = o[mt][r] * inv;
            *(f32x4*)(&Om[(pq * 16 + l16) * 68 + mt * 16 + quad * 4]) = ov;
        }
    }
    __syncthreads();
    const int orow = tid >> 3, ocf = (tid & 7) * 8;
    float* og = out + (long)(b * 2048 + qt * 64 + orow) * 64 + ocf;
#pragma unroll
    for (int j = 0; j < 2; j++)
        *(float4*)(og + j * 4) = *(float4*)(&Om[orow * 68 + ocf + j * 4]);
}

// ---------------------------------------------------------------------------
extern "C" void kernel_launch(void* const* d_in, const int* in_sizes, int n_in,
                              void* d_out, int out_size, void* d_ws, size_t ws_size,
                              hipStream_t stream) {
    const float* x  = (const float*)d_in[0];
    const float* Wq = (const float*)d_in[1];
    const float* Wk = (const float*)d_in[2];
    const float* Wv = (const float*)d_in[3];
    float* out = (float*)d_out;

    bf16* Qb  = (bf16*)d_ws;           // 32768*64
    bf16* Kb  = Qb + 2097152;
    bf16* Vtg = Kb + 2097152;          // [16][64][2048]
    bf16* Wt  = Vtg + 2097152;         // 6*192*64

    pack_w<<<288, 256, 0, stream>>>(Wq, Wk, Wv, Wt);
    qkv_proj<<<512, 512, 0, stream>>>(x, Wt, Qb, Kb, Vtg);
    flash_attn<<<512, 512, 0, stream>>>(Qb, Kb, Vtg, out);
}